// Round 1
// baseline (8367.445 us; speedup 1.0000x reference)
//
#include <hip/hip_runtime.h>
#include <math.h>

#define B_  256
#define E_  304
#define H_  304
#define G3_ 912
#define T_  512
#define P_  68
#define PD  67      // decoder output positions
#define D_  61
#define KC  76      // K chunk (304/4)
#define NT  57      // cols per block tile (3*19 gate triples)

// ---------------------------------------------------------------------------
// gi = X @ W^T + bias   for a chunk of `steps` timesteps.
// Rows m = s*256 + b  (s = chunk-local step, b = batch).
// enc mode (target==null): X row = input + b*T*E + (t0+s)*E
// dec mode: X row = emb[tok]*E, tok = (t0+s==0) ? 0 : target[b*P + t0+s]
// Grid: (steps*4, 16); block 256. Tile: 64 rows x 57 cols, K chunked by 76.
// ---------------------------------------------------------------------------
__global__ __launch_bounds__(256) void gemm_gi(
    const float* __restrict__ xsrc, const int* __restrict__ target, int t0,
    const float* __restrict__ W, const float* __restrict__ bias,
    float* __restrict__ gi)
{
    __shared__ float As[KC][68];   // transposed: As[k][row]
    __shared__ float Ws[KC][60];   // transposed: Ws[k][col]
    const int tid = threadIdx.x;
    const int m0 = blockIdx.x * 64;
    const int n0 = blockIdx.y * NT;
    const int sl = m0 >> 8;        // chunk-local step (64 | 256 so fixed per block)
    const int b0 = m0 & 255;
    const int ty = tid & 15, cb = tid >> 4;

    float acc[4][4] = {{0.f,0.f,0.f,0.f},{0.f,0.f,0.f,0.f},
                       {0.f,0.f,0.f,0.f},{0.f,0.f,0.f,0.f}};

    for (int kc = 0; kc < 4; ++kc) {
        // stage A tile: 64 rows x 76 k
        for (int f = tid; f < 64 * 19; f += 256) {
            int r = f / 19, q = f - (f / 19) * 19;
            int b = b0 + r;
            const float* ap;
            if (target == nullptr) {
                ap = xsrc + (size_t)b * (T_ * E_) + (size_t)(t0 + sl) * E_;
            } else {
                int p = t0 + sl;
                int tok = (p == 0) ? 0 : target[b * P_ + p];
                ap = xsrc + (size_t)tok * E_;
            }
            float4 v = *(const float4*)(ap + kc * KC + q * 4);
            As[q * 4 + 0][r] = v.x; As[q * 4 + 1][r] = v.y;
            As[q * 4 + 2][r] = v.z; As[q * 4 + 3][r] = v.w;
        }
        // stage W tile: 57 cols x 76 k
        for (int f = tid; f < NT * 19; f += 256) {
            int c = f / 19, q = f - (f / 19) * 19;
            float4 v = *(const float4*)(W + (size_t)(n0 + c) * E_ + kc * KC + q * 4);
            Ws[q * 4 + 0][c] = v.x; Ws[q * 4 + 1][c] = v.y;
            Ws[q * 4 + 2][c] = v.z; Ws[q * 4 + 3][c] = v.w;
        }
        __syncthreads();
        #pragma unroll 4
        for (int k = 0; k < KC; ++k) {
            float4 av = *(const float4*)&As[k][ty * 4];
            float w0 = Ws[k][cb];
            float w1 = Ws[k][cb + 16];
            float w2 = Ws[k][cb + 32];
            float w3 = (cb < 9) ? Ws[k][cb + 48] : 0.f;
            acc[0][0] += av.x * w0; acc[1][0] += av.y * w0; acc[2][0] += av.z * w0; acc[3][0] += av.w * w0;
            acc[0][1] += av.x * w1; acc[1][1] += av.y * w1; acc[2][1] += av.z * w1; acc[3][1] += av.w * w1;
            acc[0][2] += av.x * w2; acc[1][2] += av.y * w2; acc[2][2] += av.z * w2; acc[3][2] += av.w * w2;
            acc[0][3] += av.x * w3; acc[1][3] += av.y * w3; acc[2][3] += av.z * w3; acc[3][3] += av.w * w3;
        }
        __syncthreads();
    }
    #pragma unroll
    for (int r = 0; r < 4; ++r) {
        size_t m = m0 + ty * 4 + r;
        #pragma unroll
        for (int s = 0; s < 4; ++s) {
            int c = cb + 16 * s;
            if (c < NT) {
                int n = n0 + c;
                gi[m * G3_ + n] = acc[r][s] + bias[n];
            }
        }
    }
}

// ---------------------------------------------------------------------------
// One GRU step, h-side GEMM (weights in registers) + fused gates.
// Grid (16,16): bx = 19-wide gate-triple column group, by = 16-row group.
// Threads 0..227: (kc = tid/57, c = tid%57) hold Whh[col(c)][kc*76..+75] in
// VGPRs; compute 16-row partial dots reading h via wave-uniform b128 LDS.
// Gate phase combines 4 k-partials + gi + biases -> h_out (and dec store).
// ---------------------------------------------------------------------------
__global__ __launch_bounds__(256) void gru_step(
    const float* __restrict__ gi,     // [256][912] this step
    const float* __restrict__ Whh,    // [912][304]
    const float* __restrict__ bhh,    // [912]
    const float* __restrict__ h_in,   // [256][304]
    float* __restrict__ h_out,        // [256][304]
    float* __restrict__ store, int sstride)
{
    __shared__ float hs[16][H_];
    __shared__ float red[4][NT][17];
    const int tid = threadIdx.x;
    const int r0 = blockIdx.y * 16;
    const int c0 = blockIdx.x * 19;

    // stage h rows (aligned b128)
    for (int f = tid; f < 16 * KC; f += 256) {
        int r = f / KC, q = f - (f / KC) * KC;
        *(float4*)&hs[r][q * 4] = *(const float4*)(h_in + (size_t)(r0 + r) * H_ + q * 4);
    }

    const int kc = tid / NT;
    const int c = tid - kc * NT;
    const bool active = (tid < 4 * NT);
    float4 w4[19];
    if (active) {
        int g = c / 19, j = c - (c / 19) * 19;
        const float* wp = Whh + (size_t)(g * H_ + c0 + j) * H_ + kc * KC;
        #pragma unroll
        for (int q = 0; q < 19; ++q) w4[q] = *(const float4*)(wp + 4 * q);
    }
    __syncthreads();

    if (active) {
        #pragma unroll
        for (int r = 0; r < 16; ++r) {
            float a = 0.f;
            #pragma unroll
            for (int q = 0; q < 19; ++q) {
                float4 hv = *(const float4*)&hs[r][kc * KC + 4 * q];
                a += hv.x * w4[q].x + hv.y * w4[q].y + hv.z * w4[q].z + hv.w * w4[q].w;
            }
            red[kc][c][r] = a;
        }
    }
    __syncthreads();

    for (int o = tid; o < 16 * 19; o += 256) {
        int i = o / 19, j = o - (o / 19) * 19;
        int col = c0 + j;
        int m = r0 + i;
        float gh[3];
        #pragma unroll
        for (int g = 0; g < 3; ++g) {
            int cc = g * 19 + j;
            gh[g] = red[0][cc][i] + red[1][cc][i] + red[2][cc][i] + red[3][cc][i]
                    + bhh[g * H_ + col];
        }
        const float* gim = gi + (size_t)m * G3_;
        float ir = gim[col], iz = gim[H_ + col], in_ = gim[2 * H_ + col];
        float rr = 1.f / (1.f + expf(-(ir + gh[0])));
        float zz = 1.f / (1.f + expf(-(iz + gh[1])));
        float nn = tanhf(in_ + rr * gh[2]);
        float hnew = (1.f - zz) * nn + zz * hs[i][col];
        h_out[(size_t)m * H_ + col] = hnew;
        if (store) store[(size_t)m * sstride + col] = hnew;
    }
}

// ---------------------------------------------------------------------------
// logits -> softmax -> (softmax_cal, target_cal, asr_outputs)
// One wave per output row (r = b*67 + p); 4 rows per block.
// ---------------------------------------------------------------------------
__global__ __launch_bounds__(256) void logits_softmax(
    const float* __restrict__ dec_outs,   // [B*PD][H]
    const float* __restrict__ linW,       // [61][304]
    const float* __restrict__ linb,       // [61]
    const int* __restrict__ target,       // [B][P][1]
    float* __restrict__ out)
{
    __shared__ float wsm[H_][64];   // transposed W
    __shared__ float rs[4][H_];
    const int tid = threadIdx.x;
    const int wv = tid >> 6, l = tid & 63;

    // stage transposed lin_W: lanes write consecutive l -> conflict-free
    for (int f = tid; f < H_ * 64; f += 256) {
        int k = f >> 6, ll = f & 63;
        wsm[k][ll] = (ll < D_) ? linW[(size_t)ll * H_ + k] : 0.f;
    }
    const int r = blockIdx.x * 4 + wv;
    const float* rowp = dec_outs + (size_t)r * H_;
    for (int k = l; k < H_; k += 64) rs[wv][k] = rowp[k];
    __syncthreads();

    float acc = -1e30f;
    if (l < D_) {
        acc = linb[l];
        #pragma unroll 4
        for (int k = 0; k < H_; ++k) acc += rs[wv][k] * wsm[k][l];
    }
    float m = acc;
    for (int off = 32; off; off >>= 1) m = fmaxf(m, __shfl_xor(m, off));
    float e = (l < D_) ? expf(acc - m) : 0.f;
    float s = e;
    for (int off = 32; off; off >>= 1) s += __shfl_xor(s, off);
    float av = acc; int ai = l;
    for (int off = 32; off; off >>= 1) {
        float ov = __shfl_xor(av, off);
        int oi = __shfl_xor(ai, off);
        if (ov > av || (ov == av && oi < ai)) { av = ov; ai = oi; }
    }
    const int b = r / PD, p = r - (r / PD) * PD;
    const size_t OFF1 = (size_t)B_ * PD * D_;
    const size_t OFF2 = OFF1 + (size_t)B_ * PD;
    if (l < D_)        out[(size_t)r * D_ + l] = e / s;
    else if (l == D_)  out[OFF1 + r] = (float)target[b * P_ + p + 1];
    else if (l == D_ + 1) out[OFF2 + r] = (float)ai;
}

// ---------------------------------------------------------------------------
extern "C" void kernel_launch(void* const* d_in, const int* in_sizes, int n_in,
                              void* d_out, int out_size, void* d_ws, size_t ws_size,
                              hipStream_t stream)
{
    const float* input = (const float*)d_in[0];
    const int*   target = (const int*)d_in[1];
    const float* eWih = (const float*)d_in[3];
    const float* eWhh = (const float*)d_in[4];
    const float* ebih = (const float*)d_in[5];
    const float* ebhh = (const float*)d_in[6];
    const float* emb  = (const float*)d_in[7];
    const float* dWih = (const float*)d_in[8];
    const float* dWhh = (const float*)d_in[9];
    const float* dbih = (const float*)d_in[10];
    const float* dbhh = (const float*)d_in[11];
    const float* linW = (const float*)d_in[12];
    const float* linb = (const float*)d_in[13];
    float* out = (float*)d_out;

    float* ws = (float*)d_ws;
    size_t off = 0;
    float* hA = ws + off;       off += (size_t)B_ * H_;
    float* hB = ws + off;       off += (size_t)B_ * H_;
    float* dec_outs = ws + off; off += (size_t)B_ * PD * H_;
    float* gi_buf = ws + off;

    size_t remain = ws_size / 4 - off;
    int CH = (int)(remain / ((size_t)B_ * G3_));
    if (CH > PD) CH = PD;
    if (CH < 1) CH = 1;

    hipMemsetAsync(hA, 0, (size_t)B_ * H_ * sizeof(float), stream);
    float* hcur = hA;
    float* hnxt = hB;

    // ---- encoder: 512 steps, chunked gi precompute ----
    for (int t0 = 0; t0 < T_; t0 += CH) {
        int steps = (T_ - t0 < CH) ? (T_ - t0) : CH;
        dim3 ggrid(steps * 4, 16);
        gemm_gi<<<ggrid, 256, 0, stream>>>(input, nullptr, t0, eWih, ebih, gi_buf);
        for (int s = 0; s < steps; ++s) {
            gru_step<<<dim3(16, 16), 256, 0, stream>>>(
                gi_buf + (size_t)s * B_ * G3_, eWhh, ebhh, hcur, hnxt, nullptr, 0);
            float* t = hcur; hcur = hnxt; hnxt = t;
        }
    }
    // ---- decoder: 67 steps ----
    for (int p0 = 0; p0 < PD; p0 += CH) {
        int steps = (PD - p0 < CH) ? (PD - p0) : CH;
        dim3 ggrid(steps * 4, 16);
        gemm_gi<<<ggrid, 256, 0, stream>>>(emb, target, p0, dWih, dbih, gi_buf);
        for (int s = 0; s < steps; ++s) {
            gru_step<<<dim3(16, 16), 256, 0, stream>>>(
                gi_buf + (size_t)s * B_ * G3_, dWhh, dbhh, hcur, hnxt,
                dec_outs + (size_t)(p0 + s) * H_, PD * H_);
            float* t = hcur; hcur = hnxt; hnxt = t;
        }
    }
    // ---- logits / softmax / argmax ----
    logits_softmax<<<dim3(B_ * PD / 4), 256, 0, stream>>>(dec_outs, linW, linb, target, out);
}